// Round 1
// baseline (232.027 us; speedup 1.0000x reference)
//
#include <hip/hip_runtime.h>
#include <hip/hip_bf16.h>

#define FH 200
#define FW 200
#define FC 1024
#define POOL 7

__global__ __launch_bounds__(256) void roi_pool_kernel(
    const float* __restrict__ feat,   // (H, W, C)
    const int*   __restrict__ rois,   // (N, 4) = x0, y0, w, h
    float*       __restrict__ out,    // (N, POOL, POOL, C)
    int N)
{
    const int blk = blockIdx.x;
    const int n  = blk / (POOL * POOL);
    if (n >= N) return;
    const int r  = blk % (POOL * POOL);
    const int py = r / POOL;
    const int px = r % POOL;

    const int x0 = rois[4 * n + 0];
    const int y0 = rois[4 * n + 1];
    const int w  = rois[4 * n + 2];
    const int h  = rois[4 * n + 3];

    // Match reference arithmetic order exactly (fp32 throughout).
    const float ry = (float)py * ((float)h / (float)POOL);
    const float rx = (float)px * ((float)w / (float)POOL);
    const int ylo = (int)floorf(ry);
    const int xlo = (int)floorf(rx);
    const float fy = ry - (float)ylo;
    const float fx = rx - (float)xlo;
    const int yhi = min(ylo + 1, h - 1);
    const int xhi = min(xlo + 1, w - 1);

    const int iy0 = min(max(y0 + ylo, 0), FH - 1);
    const int iy1 = min(max(y0 + yhi, 0), FH - 1);
    const int ix0 = min(max(x0 + xlo, 0), FW - 1);
    const int ix1 = min(max(x0 + xhi, 0), FW - 1);

    const float4* __restrict__ p00 = (const float4*)(feat + ((size_t)iy0 * FW + ix0) * FC);
    const float4* __restrict__ p01 = (const float4*)(feat + ((size_t)iy0 * FW + ix1) * FC);
    const float4* __restrict__ p10 = (const float4*)(feat + ((size_t)iy1 * FW + ix0) * FC);
    const float4* __restrict__ p11 = (const float4*)(feat + ((size_t)iy1 * FW + ix1) * FC);

    const float wx1 = fx, wx0 = 1.0f - fx;
    const float wy1 = fy, wy0 = 1.0f - fy;

    const int t = threadIdx.x;  // 256 threads × float4 = 1024 channels

    const float4 a = p00[t];
    const float4 b = p01[t];
    const float4 c = p10[t];
    const float4 d = p11[t];

    float4 res;
    {
        const float top_x = a.x * wx0 + b.x * wx1;
        const float bot_x = c.x * wx0 + d.x * wx1;
        res.x = top_x * wy0 + bot_x * wy1;
        const float top_y = a.y * wx0 + b.y * wx1;
        const float bot_y = c.y * wx0 + d.y * wx1;
        res.y = top_y * wy0 + bot_y * wy1;
        const float top_z = a.z * wx0 + b.z * wx1;
        const float bot_z = c.z * wx0 + d.z * wx1;
        res.z = top_z * wy0 + bot_z * wy1;
        const float top_w = a.w * wx0 + b.w * wx1;
        const float bot_w = c.w * wx0 + d.w * wx1;
        res.w = top_w * wy0 + bot_w * wy1;
    }

    float4* __restrict__ o = (float4*)(out + ((size_t)blk) * FC);
    o[t] = res;
}

extern "C" void kernel_launch(void* const* d_in, const int* in_sizes, int n_in,
                              void* d_out, int out_size, void* d_ws, size_t ws_size,
                              hipStream_t stream) {
    const float* feat = (const float*)d_in[0];   // (1, 200, 200, 1024) fp32
    const int*   rois = (const int*)d_in[1];     // (300, 4) int32
    float* out = (float*)d_out;                  // (300, 7, 7, 1024) fp32

    const int N = in_sizes[1] / 4;
    const int blocks = N * POOL * POOL;
    roi_pool_kernel<<<blocks, 256, 0, stream>>>(feat, rois, out, N);
}